// Round 11
// baseline (564.432 us; speedup 1.0000x reference)
//
#include <hip/hip_runtime.h>
#include <hip/hip_bf16.h>
#include <math.h>

#define N_NODES 10000
#define D_MODEL 128
#define E_EDGES 320000
#define P_EDGES 80000
#define LN_EPS 1e-5f
#define CAP 32             // slots per bucket (Poisson(8): P(>32) ~ 1e-11)
#define NCOLS 160          // delta(128) + B(16) + C(16)
#define NT 16              // nodes per mega block (80 rows exact; 625 blocks)

typedef __attribute__((ext_vector_type(8))) short bf16x8;
typedef __attribute__((ext_vector_type(4))) float f32x4;

#if __has_builtin(__builtin_amdgcn_exp2f)
#define EXP2(x) __builtin_amdgcn_exp2f(x)
#else
#define EXP2(x) exp2f(x)
#endif
#define LOG2E 1.44269504088896f

__device__ __forceinline__ unsigned short f2bf(float f) {
    __hip_bfloat16 h = __float2bfloat16(f);
    return *reinterpret_cast<unsigned short*>(&h);
}
__device__ __forceinline__ float bf2f(unsigned int u) {
    return __uint_as_float(u << 16);
}

// ---------------------------------------------------------------------------
// prep_all (+csr folded in)
// ---------------------------------------------------------------------------
__global__ __launch_bounds__(256) void prep_all(
    const float* __restrict__ Wd, const float* __restrict__ Wb,
    const float* __restrict__ Wc, const float* __restrict__ Wg,
    const float* __restrict__ W_out,
    const float* __restrict__ x, const float* __restrict__ rel,
    const int* __restrict__ edge_index, const int* __restrict__ edge_type,
    const int* __restrict__ perms,
    unsigned short* __restrict__ Bp, unsigned short* __restrict__ Wop,
    unsigned short* __restrict__ Wgp,
    unsigned short* __restrict__ x_bf, unsigned short* __restrict__ rel_bf,
    int* __restrict__ cnt, int2* __restrict__ slots,
    unsigned short* __restrict__ tokens)
{
    int gid = blockIdx.x * 256 + threadIdx.x;
    if (gid < 20480) {                         // Bp: 128 x 160
        int k = gid / NCOLS, n = gid - (gid / NCOLS) * NCOLS;
        float v;
        if (n < 128)      v = Wd[k * 128 + n];
        else if (n < 144) v = Wb[k * 16 + (n - 128)];
        else              v = Wc[k * 16 + (n - 144)];
        Bp[((size_t)(k >> 3) * NCOLS + n) * 8 + (k & 7)] = f2bf(v);
    } else if (gid < 36864) {                  // Wop: 128 x 128
        int i = gid - 20480;
        int k = i >> 7, n = i & 127;
        Wop[((size_t)(k >> 3) * 128 + n) * 8 + (k & 7)] = f2bf(W_out[k * 128 + n]);
    } else if (gid < 53248) {                  // Wgp: 128 x 128
        int i = gid - 36864;
        int k = i >> 7, n = i & 127;
        Wgp[((size_t)(k >> 3) * 128 + n) * 8 + (k & 7)] = f2bf(Wg[k * 128 + n]);
    } else if (gid < 78848) {                  // rel_bf
        int i = gid - 53248;
        rel_bf[i] = f2bf(rel[i]);
    } else if (gid < 1358848) {                // x -> bf16 + s=0 token rows
        int i = gid - 78848;
        unsigned short v = f2bf(x[i]);
        x_bf[i] = v;
        tokens[(size_t)(i >> 7) * 640 + (i & 127)] = v;
    } else if (gid < 1678848) {                // CSR scatter (cnt pre-zeroed)
        int i = gid - 1358848;
        int s = i / P_EDGES;
        int e = perms[i];
        int src = edge_index[e];
        int dst = edge_index[E_EDGES + e];
        int ty  = edge_type[e];
        int b = dst * 4 + s;
        int pos = atomicAdd(&cnt[b], 1);
        if (pos < CAP) slots[(size_t)b * CAP + pos] = make_int2(src, ty);
    }
}

// ---------------------------------------------------------------------------
// Gather
// ---------------------------------------------------------------------------
__global__ __launch_bounds__(256) void gather_tokens(
    const unsigned short* __restrict__ x_bf,
    const int* __restrict__ cnt, const int2* __restrict__ slots,
    const unsigned short* __restrict__ rel_bf,
    unsigned short* __restrict__ tokens)
{
    int n = blockIdx.x;
    int w = threadIdx.x >> 6, lane = threadIdx.x & 63;
    int b = n * 4 + w;
    int c = cnt[b];
    int cc = c < CAP ? c : CAP;
    const int2* sl = slots + (size_t)b * CAP;
    const unsigned int* xu = (const unsigned int*)x_bf;
    const unsigned int* ru = (const unsigned int*)rel_bf;
    float ax = 0.f, ay = 0.f;
    int j = 0;
    for (; j + 4 <= cc; j += 4) {
        int4 e01 = *(const int4*)(sl + j);
        int4 e23 = *(const int4*)(sl + j + 2);
        unsigned int x0 = xu[(size_t)e01.x * 64 + lane];
        unsigned int r0 = ru[(size_t)e01.y * 64 + lane];
        unsigned int x1 = xu[(size_t)e01.z * 64 + lane];
        unsigned int r1 = ru[(size_t)e01.w * 64 + lane];
        unsigned int x2 = xu[(size_t)e23.x * 64 + lane];
        unsigned int r2 = ru[(size_t)e23.y * 64 + lane];
        unsigned int x3 = xu[(size_t)e23.z * 64 + lane];
        unsigned int r3 = ru[(size_t)e23.w * 64 + lane];
        ax += (bf2f(x0 & 0xffffu) + bf2f(r0 & 0xffffu))
            + (bf2f(x1 & 0xffffu) + bf2f(r1 & 0xffffu))
            + (bf2f(x2 & 0xffffu) + bf2f(r2 & 0xffffu))
            + (bf2f(x3 & 0xffffu) + bf2f(r3 & 0xffffu));
        ay += (bf2f(x0 >> 16) + bf2f(r0 >> 16))
            + (bf2f(x1 >> 16) + bf2f(r1 >> 16))
            + (bf2f(x2 >> 16) + bf2f(r2 >> 16))
            + (bf2f(x3 >> 16) + bf2f(r3 >> 16));
    }
    if (j + 2 <= cc) {
        int4 e01 = *(const int4*)(sl + j);
        unsigned int x0 = xu[(size_t)e01.x * 64 + lane];
        unsigned int r0 = ru[(size_t)e01.y * 64 + lane];
        unsigned int x1 = xu[(size_t)e01.z * 64 + lane];
        unsigned int r1 = ru[(size_t)e01.w * 64 + lane];
        ax += (bf2f(x0 & 0xffffu) + bf2f(r0 & 0xffffu))
            + (bf2f(x1 & 0xffffu) + bf2f(r1 & 0xffffu));
        ay += (bf2f(x0 >> 16) + bf2f(r0 >> 16))
            + (bf2f(x1 >> 16) + bf2f(r1 >> 16));
        j += 2;
    }
    if (j < cc) {
        int2 se = sl[j];
        unsigned int xa = xu[(size_t)se.x * 64 + lane];
        unsigned int ra = ru[(size_t)se.y * 64 + lane];
        ax += bf2f(xa & 0xffffu) + bf2f(ra & 0xffffu);
        ay += bf2f(xa >> 16) + bf2f(ra >> 16);
    }
    float inv = 1.f / fmaxf((float)c, 1.f);
    unsigned int pack = (unsigned int)f2bf(ax * inv)
                      | ((unsigned int)f2bf(ay * inv) << 16);
    ((unsigned int*)tokens)[((size_t)n * 5 + w + 1) * 64 + lane] = pack;
}

// ---------------------------------------------------------------------------
// MEGA: exact R8 version (best measured: 74.0 us, total 195.6).
// ---------------------------------------------------------------------------
__global__ __launch_bounds__(512, 4) void mega(
    const unsigned short* __restrict__ tokens,
    const unsigned short* __restrict__ Bp,
    const unsigned short* __restrict__ Wop,
    const unsigned short* __restrict__ Wgp,
    const unsigned short* __restrict__ x_bf,
    const float* __restrict__ x,
    const float* __restrict__ log_A,
    const float* __restrict__ b_delta, const float* __restrict__ b_g,
    const float* __restrict__ b_out,
    const float* __restrict__ ln_g, const float* __restrict__ ln_b,
    float* __restrict__ out)
{
    const int tid = threadIdx.x;
    const int wv = tid >> 6, lane = tid & 63;
    const int quad = lane >> 4, l16 = lane & 15;
    const int m0 = blockIdx.x * 80;
    const int n0 = blockIdx.x * NT;

    __shared__ __align__(16) char smem[47104];
    unsigned short* s_deltaT = (unsigned short*)smem;           // [16][128][8]
    float*          s_bcf    = (float*)(smem + 32768);          // [80][32] f32
    unsigned short* s_so     = (unsigned short*)(smem + 43008); // [16][128] swz
    float* s_res  = (float*)smem;
    float* s_pmu  = (float*)(smem + 8448);
    float* s_pv2  = (float*)(smem + 9472);
    float* s_mu   = (float*)(smem + 10496);
    float* s_rstd = (float*)(smem + 10560);

    // ---------------- phase 1
    for (int u = wv; u < 50; u += 8) {
        int f = u / 10, t = u - (u / 10) * 10;
        f32x4 acc = {0.f, 0.f, 0.f, 0.f};
        const unsigned short* arow =
            tokens + (size_t)(m0 + f * 16 + l16) * 128 + quad * 8;
        #pragma unroll
        for (int kc = 0; kc < 128; kc += 32) {
            bf16x8 a = *(const bf16x8*)(arow + kc);
            bf16x8 b = *(const bf16x8*)(Bp +
                ((size_t)(kc / 8 + quad) * NCOLS + 16 * t + l16) * 8);
            acc = __builtin_amdgcn_mfma_f32_16x16x32_bf16(a, b, acc, 0, 0, 0);
        }
        int rbase = f * 16 + quad * 4;
        int c = 16 * t + l16;
        #pragma unroll
        for (int reg = 0; reg < 4; ++reg) {
            int r = rbase + reg;
            float v = acc[reg];
            if (t < 8) {
                float z = v + b_delta[c];
                float d = (z > 15.f) ? z : log1pf(__expf(z));
                int nd = r / 5, sx = r - nd * 5;
                s_deltaT[nd * 1024 + c * 8 + sx] = f2bf(d);
            } else {
                s_bcf[r * 32 + (c - 128)] = v;
            }
        }
    }
    __syncthreads();

    // ---------------- phase 2
    {
        const int lane32 = lane & 31;
        const int khalf  = lane >> 5;
        const int dim    = ((wv & 3) << 5) | lane32;
        float Ac[8];
        {
            const float4* la = (const float4*)(log_A + dim * 16 + khalf * 8);
            float4 lv0 = la[0], lv1 = la[1];
            Ac[0] = -__expf(lv0.x) * LOG2E;
            Ac[1] = -__expf(lv0.y) * LOG2E;
            Ac[2] = -__expf(lv0.z) * LOG2E;
            Ac[3] = -__expf(lv0.w) * LOG2E;
            Ac[4] = -__expf(lv1.x) * LOG2E;
            Ac[5] = -__expf(lv1.y) * LOG2E;
            Ac[6] = -__expf(lv1.z) * LOG2E;
            Ac[7] = -__expf(lv1.w) * LOG2E;
        }
        #pragma unroll 1
        for (int i = 0; i < 8; ++i) {
            int node = (wv >> 2) + 2 * i;
            const float* bcn = s_bcf + node * 160 + khalf * 8;
            float tv[5];
            {
                const unsigned short* tb =
                    tokens + (size_t)(n0 + node) * 640 + dim;
                #pragma unroll
                for (int s = 0; s < 5; ++s) tv[s] = bf2f(tb[s * 128]);
            }
            bf16x8 dpk = *(const bf16x8*)(s_deltaT + node * 1024 + dim * 8);
            const unsigned short* dvp = (const unsigned short*)&dpk;
            float st[8], V[8];
            #pragma unroll
            for (int k = 0; k < 8; ++k) st[k] = 0.f;
            float total = 0.f;
            #pragma unroll
            for (int s = 0; s < 5; ++s) {
                float dlS = bf2f(dvp[s]);
                float dtv = dlS * tv[s];
                f32x4 Bv0 = *(const f32x4*)(bcn + s * 32);
                f32x4 Bv1 = *(const f32x4*)(bcn + s * 32 + 4);
                f32x4 Cv0 = *(const f32x4*)(bcn + s * 32 + 16);
                f32x4 Cv1 = *(const f32x4*)(bcn + s * 32 + 20);
                float yf = 0.f, ub = 0.f;
                #pragma unroll
                for (int k = 0; k < 8; ++k) {
                    float B = (k < 4) ? Bv0[k] : Bv1[k - 4];
                    float C = (k < 4) ? Cv0[k] : Cv1[k - 4];
                    float Vs = (s == 0) ? C : V[k] + C;
                    float A = EXP2(dlS * Ac[k]);
                    st[k] = fmaf(A, st[k], dtv * B);
                    yf = fmaf(st[k], C, yf);
                    ub = fmaf(Vs, B, ub);
                    V[k] = A * Vs;
                }
                total += yf + dtv * ub;
            }
            total += __shfl_xor(total, 32, 64);
            if (khalf == 0) {
                s_so[node * 128 + (((dim >> 3) ^ (node & 7)) << 3) + (dim & 7)] =
                    f2bf(total * 0.2f);
            }
        }
    }
    __syncthreads();

    // ---------------- phase 3
    {
        f32x4 accO = {0,0,0,0};
        f32x4 accG = {0,0,0,0};
        const unsigned short* grow = x_bf + (size_t)(n0 + l16) * 128 + quad * 8;
        #pragma unroll
        for (int kc = 0; kc < 128; kc += 32) {
            bf16x8 a = *(const bf16x8*)(s_so + l16 * 128 +
                           (((kc / 8 + quad) ^ (l16 & 7)) << 3));
            bf16x8 ag = *(const bf16x8*)(grow + kc);
            size_t bi = ((size_t)(kc / 8 + quad) * 128 + 16 * wv + l16) * 8;
            bf16x8 bo = *(const bf16x8*)(Wop + bi);
            bf16x8 bg = *(const bf16x8*)(Wgp + bi);
            accO = __builtin_amdgcn_mfma_f32_16x16x32_bf16(a,  bo, accO, 0, 0, 0);
            accG = __builtin_amdgcn_mfma_f32_16x16x32_bf16(ag, bg, accG, 0, 0, 0);
        }

        {
            int c = wv * 16 + l16;
            #pragma unroll
            for (int reg = 0; reg < 4; ++reg) {
                int lrow = quad * 4 + reg;
                float o  = accO[reg] + b_out[c];
                float gl = accG[reg] + b_g[c];
                float gate = gl / (1.f + __expf(-gl));
                s_res[lrow * 132 + c] = x[(size_t)(n0 + lrow) * 128 + c] + gate * o;
            }
        }
        __syncthreads();

        if (tid < 256) {
            int row = tid >> 4, q = tid & 15;
            float s = 0.f, s2 = 0.f;
            #pragma unroll
            for (int i = 0; i < 8; ++i) {
                float vv = s_res[row * 132 + q + 16 * i];
                s += vv; s2 += vv * vv;
            }
            s_pmu[row * 16 + q] = s; s_pv2[row * 16 + q] = s2;
        }
        __syncthreads();
        if (tid < 16) {
            float s = 0.f, s2 = 0.f;
            #pragma unroll
            for (int i = 0; i < 16; ++i) { s += s_pmu[tid * 16 + i]; s2 += s_pv2[tid * 16 + i]; }
            float mu = s * (1.f / 128.f);
            float var = s2 * (1.f / 128.f) - mu * mu;
            s_mu[tid] = mu;
            s_rstd[tid] = rsqrtf(var + LN_EPS);
        }
        __syncthreads();
        #pragma unroll
        for (int i = 0; i < 4; ++i) {
            int idx = i * 512 + tid;
            int row = idx >> 7, c = idx & 127;
            out[(size_t)(n0 + row) * 128 + c] =
                (s_res[row * 132 + c] - s_mu[row]) * s_rstd[row] * ln_g[c] + ln_b[c];
        }
    }
}

// ---------------------------------------------------------------------------
// PROBE 1: phase-1 body x8 reps -> dur/8 = phase-1 time. Writes checksum to
// scratch; asm memory clobber between reps blocks LICM/collapse (rule 17).
// ---------------------------------------------------------------------------
__global__ __launch_bounds__(512, 4) void probe1(
    const unsigned short* __restrict__ tokens,
    const unsigned short* __restrict__ Bp,
    const float* __restrict__ b_delta,
    float* __restrict__ scratch)
{
    const int tid = threadIdx.x;
    const int wv = tid >> 6, lane = tid & 63;
    const int quad = lane >> 4, l16 = lane & 15;
    const int m0 = blockIdx.x * 80;

    __shared__ __align__(16) char smem[43008];
    unsigned short* s_deltaT = (unsigned short*)smem;           // [16][128][8]
    float*          s_bcf    = (float*)(smem + 32768);          // [80][32]

    float live = 0.f;
    #pragma unroll 1
    for (int rep = 0; rep < 8; ++rep) {
        for (int u = wv; u < 50; u += 8) {
            int f = u / 10, t = u - (u / 10) * 10;
            f32x4 acc = {0.f, 0.f, 0.f, 0.f};
            const unsigned short* arow =
                tokens + (size_t)(m0 + f * 16 + l16) * 128 + quad * 8;
            #pragma unroll
            for (int kc = 0; kc < 128; kc += 32) {
                bf16x8 a = *(const bf16x8*)(arow + kc);
                bf16x8 b = *(const bf16x8*)(Bp +
                    ((size_t)(kc / 8 + quad) * NCOLS + 16 * t + l16) * 8);
                acc = __builtin_amdgcn_mfma_f32_16x16x32_bf16(a, b, acc, 0, 0, 0);
            }
            int rbase = f * 16 + quad * 4;
            int c = 16 * t + l16;
            #pragma unroll
            for (int reg = 0; reg < 4; ++reg) {
                int r = rbase + reg;
                float v = acc[reg];
                if (t < 8) {
                    float z = v + b_delta[c];
                    float d = (z > 15.f) ? z : log1pf(__expf(z));
                    int nd = r / 5, sx = r - nd * 5;
                    s_deltaT[nd * 1024 + c * 8 + sx] = f2bf(d);
                } else {
                    s_bcf[r * 32 + (c - 128)] = v;
                }
            }
            live += acc[0];
        }
        asm volatile("" : "+v"(live));
        asm volatile("" ::: "memory");
    }
    __syncthreads();
    scratch[(size_t)blockIdx.x * 512 + tid] =
        live + s_bcf[(tid * 5) % 2560] + bf2f(s_deltaT[(tid * 32) % 16384]);
}

// ---------------------------------------------------------------------------
// PROBE 12: (phase-1 + phase-2) x2 reps -> dur/2 = p1+p2.
// ---------------------------------------------------------------------------
__global__ __launch_bounds__(512, 4) void probe12(
    const unsigned short* __restrict__ tokens,
    const unsigned short* __restrict__ Bp,
    const float* __restrict__ b_delta,
    const float* __restrict__ log_A,
    float* __restrict__ scratch)
{
    const int tid = threadIdx.x;
    const int wv = tid >> 6, lane = tid & 63;
    const int quad = lane >> 4, l16 = lane & 15;
    const int m0 = blockIdx.x * 80;
    const int n0 = blockIdx.x * NT;

    __shared__ __align__(16) char smem[47104];
    unsigned short* s_deltaT = (unsigned short*)smem;
    float*          s_bcf    = (float*)(smem + 32768);
    unsigned short* s_so     = (unsigned short*)(smem + 43008);

    float live = 0.f;
    #pragma unroll 1
    for (int rep = 0; rep < 2; ++rep) {
        // ----- phase 1 -----
        for (int u = wv; u < 50; u += 8) {
            int f = u / 10, t = u - (u / 10) * 10;
            f32x4 acc = {0.f, 0.f, 0.f, 0.f};
            const unsigned short* arow =
                tokens + (size_t)(m0 + f * 16 + l16) * 128 + quad * 8;
            #pragma unroll
            for (int kc = 0; kc < 128; kc += 32) {
                bf16x8 a = *(const bf16x8*)(arow + kc);
                bf16x8 b = *(const bf16x8*)(Bp +
                    ((size_t)(kc / 8 + quad) * NCOLS + 16 * t + l16) * 8);
                acc = __builtin_amdgcn_mfma_f32_16x16x32_bf16(a, b, acc, 0, 0, 0);
            }
            int rbase = f * 16 + quad * 4;
            int c = 16 * t + l16;
            #pragma unroll
            for (int reg = 0; reg < 4; ++reg) {
                int r = rbase + reg;
                float v = acc[reg];
                if (t < 8) {
                    float z = v + b_delta[c];
                    float d = (z > 15.f) ? z : log1pf(__expf(z));
                    int nd = r / 5, sx = r - nd * 5;
                    s_deltaT[nd * 1024 + c * 8 + sx] = f2bf(d);
                } else {
                    s_bcf[r * 32 + (c - 128)] = v;
                }
            }
            live += acc[0];
        }
        __syncthreads();
        // ----- phase 2 -----
        {
            const int lane32 = lane & 31;
            const int khalf  = lane >> 5;
            const int dim    = ((wv & 3) << 5) | lane32;
            float Ac[8];
            {
                const float4* la = (const float4*)(log_A + dim * 16 + khalf * 8);
                float4 lv0 = la[0], lv1 = la[1];
                Ac[0] = -__expf(lv0.x) * LOG2E;
                Ac[1] = -__expf(lv0.y) * LOG2E;
                Ac[2] = -__expf(lv0.z) * LOG2E;
                Ac[3] = -__expf(lv0.w) * LOG2E;
                Ac[4] = -__expf(lv1.x) * LOG2E;
                Ac[5] = -__expf(lv1.y) * LOG2E;
                Ac[6] = -__expf(lv1.z) * LOG2E;
                Ac[7] = -__expf(lv1.w) * LOG2E;
            }
            #pragma unroll 1
            for (int i = 0; i < 8; ++i) {
                int node = (wv >> 2) + 2 * i;
                const float* bcn = s_bcf + node * 160 + khalf * 8;
                float tv[5];
                {
                    const unsigned short* tb =
                        tokens + (size_t)(n0 + node) * 640 + dim;
                    #pragma unroll
                    for (int s = 0; s < 5; ++s) tv[s] = bf2f(tb[s * 128]);
                }
                bf16x8 dpk = *(const bf16x8*)(s_deltaT + node * 1024 + dim * 8);
                const unsigned short* dvp = (const unsigned short*)&dpk;
                float st[8], V[8];
                #pragma unroll
                for (int k = 0; k < 8; ++k) st[k] = 0.f;
                float total = 0.f;
                #pragma unroll
                for (int s = 0; s < 5; ++s) {
                    float dlS = bf2f(dvp[s]);
                    float dtv = dlS * tv[s];
                    f32x4 Bv0 = *(const f32x4*)(bcn + s * 32);
                    f32x4 Bv1 = *(const f32x4*)(bcn + s * 32 + 4);
                    f32x4 Cv0 = *(const f32x4*)(bcn + s * 32 + 16);
                    f32x4 Cv1 = *(const f32x4*)(bcn + s * 32 + 20);
                    float yf = 0.f, ub = 0.f;
                    #pragma unroll
                    for (int k = 0; k < 8; ++k) {
                        float B = (k < 4) ? Bv0[k] : Bv1[k - 4];
                        float C = (k < 4) ? Cv0[k] : Cv1[k - 4];
                        float Vs = (s == 0) ? C : V[k] + C;
                        float A = EXP2(dlS * Ac[k]);
                        st[k] = fmaf(A, st[k], dtv * B);
                        yf = fmaf(st[k], C, yf);
                        ub = fmaf(Vs, B, ub);
                        V[k] = A * Vs;
                    }
                    total += yf + dtv * ub;
                }
                total += __shfl_xor(total, 32, 64);
                if (khalf == 0) {
                    s_so[node * 128 + (((dim >> 3) ^ (node & 7)) << 3) + (dim & 7)] =
                        f2bf(total * 0.2f);
                }
            }
        }
        __syncthreads();
        asm volatile("" : "+v"(live));
        asm volatile("" ::: "memory");
    }
    scratch[(size_t)blockIdx.x * 512 + tid] =
        live + bf2f(s_so[(tid * 8) % 2048]);
}

// ---------------------------------------------------------------------------
extern "C" void kernel_launch(void* const* d_in, const int* in_sizes, int n_in,
                              void* d_out, int out_size, void* d_ws, size_t ws_size,
                              hipStream_t stream) {
    const float* x          = (const float*)d_in[0];
    const int*   edge_index = (const int*)  d_in[1];
    const int*   edge_type  = (const int*)  d_in[2];
    const int*   perms      = (const int*)  d_in[3];
    const float* rel_table  = (const float*)d_in[4];
    const float* log_A      = (const float*)d_in[5];
    const float* W_B        = (const float*)d_in[6];
    const float* W_C        = (const float*)d_in[7];
    const float* W_delta    = (const float*)d_in[8];
    const float* b_delta    = (const float*)d_in[9];
    const float* W_g        = (const float*)d_in[10];
    const float* b_g        = (const float*)d_in[11];
    const float* W_out      = (const float*)d_in[12];
    const float* b_out      = (const float*)d_in[13];
    const float* ln_g       = (const float*)d_in[14];
    const float* ln_b       = (const float*)d_in[15];

    char* ws = (char*)d_ws;
    int*            cnt    = (int*)           (ws + 0);          //   163840
    unsigned short* Bp     = (unsigned short*)(ws + 163840);     //    40960
    unsigned short* Wop    = (unsigned short*)(ws + 204800);     //    32768
    unsigned short* Wgp    = (unsigned short*)(ws + 237568);     //    32768
    unsigned short* x_bf   = (unsigned short*)(ws + 270336);     //  2560000
    unsigned short* rel_bf = (unsigned short*)(ws + 2830336);    //    51200
    unsigned short* tokens = (unsigned short*)(ws + 2881536);    // 12800000
    int2*           slots  = (int2*)          (ws + 15683584);   // 10485760
    float*          scr1   = (float*)         (ws + 26169344);   //  1280000
    float*          scr2   = (float*)         (ws + 27449344);   //  1280000

    (void)hipMemsetAsync(cnt, 0, 163840, stream);

    prep_all<<<6558, 256, 0, stream>>>(
        W_delta, W_B, W_C, W_g, W_out, x, rel_table, edge_index, edge_type,
        perms, Bp, Wop, Wgp, x_bf, rel_bf, cnt, slots, tokens);

    gather_tokens<<<N_NODES, 256, 0, stream>>>(
        x_bf, cnt, slots, rel_bf, tokens);

    mega<<<N_NODES / NT, 512, 0, stream>>>(
        tokens, Bp, Wop, Wgp, x_bf, x, log_A, b_delta, b_g, b_out,
        ln_g, ln_b, (float*)d_out);

    // ---- instrumentation (this round only): phase attribution probes ----
    probe1<<<N_NODES / NT, 512, 0, stream>>>(tokens, Bp, b_delta, scr1);
    probe12<<<N_NODES / NT, 512, 0, stream>>>(tokens, Bp, b_delta, log_A, scr2);
}

// Round 12
// 176.275 us; speedup vs baseline: 3.2020x; 3.2020x over previous
//
#include <hip/hip_runtime.h>
#include <hip/hip_bf16.h>
#include <math.h>

#define N_NODES 10000
#define D_MODEL 128
#define E_EDGES 320000
#define P_EDGES 80000
#define LN_EPS 1e-5f
#define CAP 32             // slots per bucket (Poisson(8): P(>32) ~ 1e-11)
#define NCOLS 160          // delta(128) + B(16) + C(16)
#define NT 16              // nodes per mega block (80 rows exact; 625 blocks)

typedef __attribute__((ext_vector_type(8))) short bf16x8;
typedef __attribute__((ext_vector_type(4))) float f32x4;

#if __has_builtin(__builtin_amdgcn_exp2f)
#define EXP2(x) __builtin_amdgcn_exp2f(x)
#else
#define EXP2(x) exp2f(x)
#endif
#define LOG2E 1.44269504088896f

__device__ __forceinline__ unsigned short f2bf(float f) {
    __hip_bfloat16 h = __float2bfloat16(f);
    return *reinterpret_cast<unsigned short*>(&h);
}
__device__ __forceinline__ float bf2f(unsigned int u) {
    return __uint_as_float(u << 16);
}

// ---------------------------------------------------------------------------
// prep_all (+csr folded in)
// ---------------------------------------------------------------------------
__global__ __launch_bounds__(256) void prep_all(
    const float* __restrict__ Wd, const float* __restrict__ Wb,
    const float* __restrict__ Wc, const float* __restrict__ Wg,
    const float* __restrict__ W_out,
    const float* __restrict__ x, const float* __restrict__ rel,
    const int* __restrict__ edge_index, const int* __restrict__ edge_type,
    const int* __restrict__ perms,
    unsigned short* __restrict__ Bp, unsigned short* __restrict__ Wop,
    unsigned short* __restrict__ Wgp,
    unsigned short* __restrict__ x_bf, unsigned short* __restrict__ rel_bf,
    int* __restrict__ cnt, int2* __restrict__ slots,
    unsigned short* __restrict__ tokens)
{
    int gid = blockIdx.x * 256 + threadIdx.x;
    if (gid < 20480) {                         // Bp: 128 x 160
        int k = gid / NCOLS, n = gid - (gid / NCOLS) * NCOLS;
        float v;
        if (n < 128)      v = Wd[k * 128 + n];
        else if (n < 144) v = Wb[k * 16 + (n - 128)];
        else              v = Wc[k * 16 + (n - 144)];
        Bp[((size_t)(k >> 3) * NCOLS + n) * 8 + (k & 7)] = f2bf(v);
    } else if (gid < 36864) {                  // Wop: 128 x 128
        int i = gid - 20480;
        int k = i >> 7, n = i & 127;
        Wop[((size_t)(k >> 3) * 128 + n) * 8 + (k & 7)] = f2bf(W_out[k * 128 + n]);
    } else if (gid < 53248) {                  // Wgp: 128 x 128
        int i = gid - 36864;
        int k = i >> 7, n = i & 127;
        Wgp[((size_t)(k >> 3) * 128 + n) * 8 + (k & 7)] = f2bf(Wg[k * 128 + n]);
    } else if (gid < 78848) {                  // rel_bf
        int i = gid - 53248;
        rel_bf[i] = f2bf(rel[i]);
    } else if (gid < 1358848) {                // x -> bf16 + s=0 token rows
        int i = gid - 78848;
        unsigned short v = f2bf(x[i]);
        x_bf[i] = v;
        tokens[(size_t)(i >> 7) * 640 + (i & 127)] = v;
    } else if (gid < 1678848) {                // CSR scatter (cnt pre-zeroed)
        int i = gid - 1358848;
        int s = i / P_EDGES;
        int e = perms[i];
        int src = edge_index[e];
        int dst = edge_index[E_EDGES + e];
        int ty  = edge_type[e];
        int b = dst * 4 + s;
        int pos = atomicAdd(&cnt[b], 1);
        if (pos < CAP) slots[(size_t)b * CAP + pos] = make_int2(src, ty);
    }
}

// ---------------------------------------------------------------------------
// Gather
// ---------------------------------------------------------------------------
__global__ __launch_bounds__(256) void gather_tokens(
    const unsigned short* __restrict__ x_bf,
    const int* __restrict__ cnt, const int2* __restrict__ slots,
    const unsigned short* __restrict__ rel_bf,
    unsigned short* __restrict__ tokens)
{
    int n = blockIdx.x;
    int w = threadIdx.x >> 6, lane = threadIdx.x & 63;
    int b = n * 4 + w;
    int c = cnt[b];
    int cc = c < CAP ? c : CAP;
    const int2* sl = slots + (size_t)b * CAP;
    const unsigned int* xu = (const unsigned int*)x_bf;
    const unsigned int* ru = (const unsigned int*)rel_bf;
    float ax = 0.f, ay = 0.f;
    int j = 0;
    for (; j + 4 <= cc; j += 4) {
        int4 e01 = *(const int4*)(sl + j);
        int4 e23 = *(const int4*)(sl + j + 2);
        unsigned int x0 = xu[(size_t)e01.x * 64 + lane];
        unsigned int r0 = ru[(size_t)e01.y * 64 + lane];
        unsigned int x1 = xu[(size_t)e01.z * 64 + lane];
        unsigned int r1 = ru[(size_t)e01.w * 64 + lane];
        unsigned int x2 = xu[(size_t)e23.x * 64 + lane];
        unsigned int r2 = ru[(size_t)e23.y * 64 + lane];
        unsigned int x3 = xu[(size_t)e23.z * 64 + lane];
        unsigned int r3 = ru[(size_t)e23.w * 64 + lane];
        ax += (bf2f(x0 & 0xffffu) + bf2f(r0 & 0xffffu))
            + (bf2f(x1 & 0xffffu) + bf2f(r1 & 0xffffu))
            + (bf2f(x2 & 0xffffu) + bf2f(r2 & 0xffffu))
            + (bf2f(x3 & 0xffffu) + bf2f(r3 & 0xffffu));
        ay += (bf2f(x0 >> 16) + bf2f(r0 >> 16))
            + (bf2f(x1 >> 16) + bf2f(r1 >> 16))
            + (bf2f(x2 >> 16) + bf2f(r2 >> 16))
            + (bf2f(x3 >> 16) + bf2f(r3 >> 16));
    }
    if (j + 2 <= cc) {
        int4 e01 = *(const int4*)(sl + j);
        unsigned int x0 = xu[(size_t)e01.x * 64 + lane];
        unsigned int r0 = ru[(size_t)e01.y * 64 + lane];
        unsigned int x1 = xu[(size_t)e01.z * 64 + lane];
        unsigned int r1 = ru[(size_t)e01.w * 64 + lane];
        ax += (bf2f(x0 & 0xffffu) + bf2f(r0 & 0xffffu))
            + (bf2f(x1 & 0xffffu) + bf2f(r1 & 0xffffu));
        ay += (bf2f(x0 >> 16) + bf2f(r0 >> 16))
            + (bf2f(x1 >> 16) + bf2f(r1 >> 16));
        j += 2;
    }
    if (j < cc) {
        int2 se = sl[j];
        unsigned int xa = xu[(size_t)se.x * 64 + lane];
        unsigned int ra = ru[(size_t)se.y * 64 + lane];
        ax += bf2f(xa & 0xffffu) + bf2f(ra & 0xffffu);
        ay += bf2f(xa >> 16) + bf2f(ra >> 16);
    }
    float inv = 1.f / fmaxf((float)c, 1.f);
    unsigned int pack = (unsigned int)f2bf(ax * inv)
                      | ((unsigned int)f2bf(ay * inv) << 16);
    ((unsigned int*)tokens)[((size_t)n * 5 + w + 1) * 64 + lane] = pack;
}

// ---------------------------------------------------------------------------
// MEGA: gemm1 + scan + out fused per 16-node block.
// R11: probe showed phase-1 = 34.5us of 74 (global A-load latency chains +
// libm softplus), phase-2 had 40 scalar global tv loads. Fix: stage the
// 80x128 token tile in LDS ONCE (coalesced reg-staged, XOR-swizzled
// byte^=(row&7)<<4 for conflict-free ds_read_b128), phase-1 A-frags and
// phase-2 tv both read LDS; softplus via __logf (HW log, bf16-exact enough).
// LDS 66KB (gfx950 allows 160KB) -> 2 blocks/CU.
// ---------------------------------------------------------------------------
__global__ __launch_bounds__(512, 4) void mega(
    const unsigned short* __restrict__ tokens,
    const unsigned short* __restrict__ Bp,
    const unsigned short* __restrict__ Wop,
    const unsigned short* __restrict__ Wgp,
    const unsigned short* __restrict__ x_bf,
    const float* __restrict__ x,
    const float* __restrict__ log_A,
    const float* __restrict__ b_delta, const float* __restrict__ b_g,
    const float* __restrict__ b_out,
    const float* __restrict__ ln_g, const float* __restrict__ ln_b,
    float* __restrict__ out)
{
    const int tid = threadIdx.x;
    const int wv = tid >> 6, lane = tid & 63;
    const int quad = lane >> 4, l16 = lane & 15;
    const int m0 = blockIdx.x * 80;
    const int n0 = blockIdx.x * NT;

    // LDS map: s_A 0..20480 (swz tokens tile) | deltaT 20480..53248 |
    // bcf 53248..63488 | so 63488..67584. Phase-3 res/pmu/... alias s_A.
    __shared__ __align__(16) char smem[67584];
    unsigned short* s_deltaT = (unsigned short*)(smem + 20480);  // [16][128][8]
    float*          s_bcf    = (float*)(smem + 53248);           // [80][32] f32
    unsigned short* s_so     = (unsigned short*)(smem + 63488);  // [16][128] swz
    float* s_res  = (float*)smem;                                // [16][132]
    float* s_pmu  = (float*)(smem + 8448);
    float* s_pv2  = (float*)(smem + 9472);
    float* s_mu   = (float*)(smem + 10496);
    float* s_rstd = (float*)(smem + 10560);

    // ---------------- phase 0: stage token tile -> s_A (swizzled)
    // 80 rows x 256B = 1280 x 16B chunks; 512 threads x 2.5 -> 3 guarded passes.
    {
        const uint4* gsrc = (const uint4*)(tokens + (size_t)m0 * 128);
        #pragma unroll
        for (int p = 0; p < 3; ++p) {
            int idx = p * 512 + tid;
            if (idx < 1280) {
                uint4 v = gsrc[idx];
                int swz = (idx * 16) ^ (((idx >> 4) & 7) << 4);  // row = idx>>4
                *(uint4*)(smem + swz) = v;
            }
        }
    }
    __syncthreads();

    // ---------------- phase 1: GEMM1  Z[80,160] -> s_deltaT | s_bcf
    for (int u = wv; u < 50; u += 8) {
        int f = u / 10, t = u - (u / 10) * 10;
        f32x4 acc = {0.f, 0.f, 0.f, 0.f};
        const int arow_l = f * 16 + l16;
        const int abase  = arow_l * 256 + quad * 16;
        const int aswz   = (arow_l & 7) << 4;
        #pragma unroll
        for (int kc = 0; kc < 128; kc += 32) {
            bf16x8 a = *(const bf16x8*)(smem + ((abase + kc * 2) ^ aswz));
            bf16x8 b = *(const bf16x8*)(Bp +
                ((size_t)(kc / 8 + quad) * NCOLS + 16 * t + l16) * 8);
            acc = __builtin_amdgcn_mfma_f32_16x16x32_bf16(a, b, acc, 0, 0, 0);
        }
        int rbase = f * 16 + quad * 4;
        int c = 16 * t + l16;
        #pragma unroll
        for (int reg = 0; reg < 4; ++reg) {
            int r = rbase + reg;
            float v = acc[reg];
            if (t < 8) {
                float z = v + b_delta[c];
                float d = (z > 15.f) ? z : __logf(1.f + __expf(z));
                int nd = r / 5, sx = r - nd * 5;
                s_deltaT[nd * 1024 + c * 8 + sx] = f2bf(d);
            } else {
                s_bcf[r * 32 + (c - 128)] = v;
            }
        }
    }
    __syncthreads();

    // ---------------- phase 2: bidirectional selective scan -> s_so
    // k-split: khalf = lane>>5 owns 8 of 16 k-slots; combine via shfl_xor.
    // tv and dl both from LDS now (no global loads in this phase).
    {
        const int lane32 = lane & 31;
        const int khalf  = lane >> 5;
        const int dim    = ((wv & 3) << 5) | lane32;
        float Ac[8];
        {
            const float4* la = (const float4*)(log_A + dim * 16 + khalf * 8);
            float4 lv0 = la[0], lv1 = la[1];
            Ac[0] = -__expf(lv0.x) * LOG2E;
            Ac[1] = -__expf(lv0.y) * LOG2E;
            Ac[2] = -__expf(lv0.z) * LOG2E;
            Ac[3] = -__expf(lv0.w) * LOG2E;
            Ac[4] = -__expf(lv1.x) * LOG2E;
            Ac[5] = -__expf(lv1.y) * LOG2E;
            Ac[6] = -__expf(lv1.z) * LOG2E;
            Ac[7] = -__expf(lv1.w) * LOG2E;
        }
        #pragma unroll 1
        for (int i = 0; i < 8; ++i) {
            int node = (wv >> 2) + 2 * i;
            const float* bcn = s_bcf + node * 160 + khalf * 8;
            float tv[5];
            #pragma unroll
            for (int s = 0; s < 5; ++s) {
                int r = node * 5 + s;
                tv[s] = bf2f(*(const unsigned short*)(smem +
                            ((r * 256 + dim * 2) ^ ((r & 7) << 4))));
            }
            bf16x8 dpk = *(const bf16x8*)(s_deltaT + node * 1024 + dim * 8);
            const unsigned short* dvp = (const unsigned short*)&dpk;
            float st[8], V[8];
            #pragma unroll
            for (int k = 0; k < 8; ++k) st[k] = 0.f;
            float total = 0.f;
            #pragma unroll
            for (int s = 0; s < 5; ++s) {
                float dlS = bf2f(dvp[s]);
                float dtv = dlS * tv[s];
                f32x4 Bv0 = *(const f32x4*)(bcn + s * 32);
                f32x4 Bv1 = *(const f32x4*)(bcn + s * 32 + 4);
                f32x4 Cv0 = *(const f32x4*)(bcn + s * 32 + 16);
                f32x4 Cv1 = *(const f32x4*)(bcn + s * 32 + 20);
                float yf = 0.f, ub = 0.f;
                #pragma unroll
                for (int k = 0; k < 8; ++k) {
                    float B = (k < 4) ? Bv0[k] : Bv1[k - 4];
                    float C = (k < 4) ? Cv0[k] : Cv1[k - 4];
                    float Vs = (s == 0) ? C : V[k] + C;
                    float A = EXP2(dlS * Ac[k]);
                    st[k] = fmaf(A, st[k], dtv * B);
                    yf = fmaf(st[k], C, yf);
                    ub = fmaf(Vs, B, ub);
                    V[k] = A * Vs;
                }
                total += yf + dtv * ub;
            }
            total += __shfl_xor(total, 32, 64);
            if (khalf == 0) {
                s_so[node * 128 + (((dim >> 3) ^ (node & 7)) << 3) + (dim & 7)] =
                    f2bf(total * 0.2f);
            }
        }
    }
    __syncthreads();

    // ---------------- phase 3: out = LN(x + silu(x@Wg+bg)*(so@Wo+bo))
    {
        f32x4 accO = {0,0,0,0};
        f32x4 accG = {0,0,0,0};
        const unsigned short* grow = x_bf + (size_t)(n0 + l16) * 128 + quad * 8;
        #pragma unroll
        for (int kc = 0; kc < 128; kc += 32) {
            bf16x8 a = *(const bf16x8*)(s_so + l16 * 128 +
                           (((kc / 8 + quad) ^ (l16 & 7)) << 3));
            bf16x8 ag = *(const bf16x8*)(grow + kc);
            size_t bi = ((size_t)(kc / 8 + quad) * 128 + 16 * wv + l16) * 8;
            bf16x8 bo = *(const bf16x8*)(Wop + bi);
            bf16x8 bg = *(const bf16x8*)(Wgp + bi);
            accO = __builtin_amdgcn_mfma_f32_16x16x32_bf16(a,  bo, accO, 0, 0, 0);
            accG = __builtin_amdgcn_mfma_f32_16x16x32_bf16(ag, bg, accG, 0, 0, 0);
        }

        {
            int c = wv * 16 + l16;
            #pragma unroll
            for (int reg = 0; reg < 4; ++reg) {
                int lrow = quad * 4 + reg;
                float o  = accO[reg] + b_out[c];
                float gl = accG[reg] + b_g[c];
                float gate = gl / (1.f + __expf(-gl));
                s_res[lrow * 132 + c] = x[(size_t)(n0 + lrow) * 128 + c] + gate * o;
            }
        }
        __syncthreads();

        if (tid < 256) {
            int row = tid >> 4, q = tid & 15;
            float s = 0.f, s2 = 0.f;
            #pragma unroll
            for (int i = 0; i < 8; ++i) {
                float vv = s_res[row * 132 + q + 16 * i];
                s += vv; s2 += vv * vv;
            }
            s_pmu[row * 16 + q] = s; s_pv2[row * 16 + q] = s2;
        }
        __syncthreads();
        if (tid < 16) {
            float s = 0.f, s2 = 0.f;
            #pragma unroll
            for (int i = 0; i < 16; ++i) { s += s_pmu[tid * 16 + i]; s2 += s_pv2[tid * 16 + i]; }
            float mu = s * (1.f / 128.f);
            float var = s2 * (1.f / 128.f) - mu * mu;
            s_mu[tid] = mu;
            s_rstd[tid] = rsqrtf(var + LN_EPS);
        }
        __syncthreads();
        #pragma unroll
        for (int i = 0; i < 4; ++i) {
            int idx = i * 512 + tid;
            int row = idx >> 7, c = idx & 127;
            out[(size_t)(n0 + row) * 128 + c] =
                (s_res[row * 132 + c] - s_mu[row]) * s_rstd[row] * ln_g[c] + ln_b[c];
        }
    }
}

// ---------------------------------------------------------------------------
extern "C" void kernel_launch(void* const* d_in, const int* in_sizes, int n_in,
                              void* d_out, int out_size, void* d_ws, size_t ws_size,
                              hipStream_t stream) {
    const float* x          = (const float*)d_in[0];
    const int*   edge_index = (const int*)  d_in[1];
    const int*   edge_type  = (const int*)  d_in[2];
    const int*   perms      = (const int*)  d_in[3];
    const float* rel_table  = (const float*)d_in[4];
    const float* log_A      = (const float*)d_in[5];
    const float* W_B        = (const float*)d_in[6];
    const float* W_C        = (const float*)d_in[7];
    const float* W_delta    = (const float*)d_in[8];
    const float* b_delta    = (const float*)d_in[9];
    const float* W_g        = (const float*)d_in[10];
    const float* b_g        = (const float*)d_in[11];
    const float* W_out      = (const float*)d_in[12];
    const float* b_out      = (const float*)d_in[13];
    const float* ln_g       = (const float*)d_in[14];
    const float* ln_b       = (const float*)d_in[15];

    char* ws = (char*)d_ws;
    int*            cnt    = (int*)           (ws + 0);          //   163840
    unsigned short* Bp     = (unsigned short*)(ws + 163840);     //    40960
    unsigned short* Wop    = (unsigned short*)(ws + 204800);     //    32768
    unsigned short* Wgp    = (unsigned short*)(ws + 237568);     //    32768
    unsigned short* x_bf   = (unsigned short*)(ws + 270336);     //  2560000
    unsigned short* rel_bf = (unsigned short*)(ws + 2830336);    //    51200
    unsigned short* tokens = (unsigned short*)(ws + 2881536);    // 12800000
    int2*           slots  = (int2*)          (ws + 15683584);   // 10485760

    (void)hipMemsetAsync(cnt, 0, 163840, stream);

    prep_all<<<6558, 256, 0, stream>>>(
        W_delta, W_B, W_C, W_g, W_out, x, rel_table, edge_index, edge_type,
        perms, Bp, Wop, Wgp, x_bf, rel_bf, cnt, slots, tokens);

    gather_tokens<<<N_NODES, 256, 0, stream>>>(
        x_bf, cnt, slots, rel_bf, tokens);

    mega<<<N_NODES / NT, 512, 0, stream>>>(
        tokens, Bp, Wop, Wgp, x_bf, x, log_A, b_delta, b_g, b_out,
        ln_g, ln_b, (float*)d_out);
}